// Round 15
// baseline (39.842 us; speedup 1.0000x reference)
//
#include <hip/hip_runtime.h>
#include <math.h>

#define C_DIM 128
#define H_DIM 128
#define W_DIM 128
#define HW (H_DIM * W_DIM)
#define EPS_N 1e-12f
#define NSL 4                   // channel slices (K2) / channel groups (K3)
#define CPS (C_DIM / NSL)       // 32 channels per slice
#define NPL 11                  // planes per (row,slice): 9 dots + fe2 + norm2
#define PS (NPL * W_DIM)        // 1408 floats per (row,slice)
#define LD4(p) (*(const float4*)(p))

// ---------------- K2: per-slice partial dots + fe2 + own-row fu-norm^2 ----------------
// Block = (row, slice): 256 thr = 4 waves x 8 channels. R4-measured float4 lane
// mapping: li = l&31 owns px 4li..4li+3, sub = l>>5 = channel parity; li-masked
// width-boundary shuffles; shfl_xor(32) parity combine. R10-measured partials
// plumbing. 2 iterations of 8 float4 loads (128 B/lane in flight).
__global__ __launch_bounds__(256) void k2_partial4(const float* __restrict__ fe,
                                                   const float* __restrict__ fu,
                                                   float* __restrict__ pg)
{
    __shared__ float pl[4][PS];   // 22 KB per-wave partial slots

    const int tid = threadIdx.x;
    const int l   = tid & 63;
    const int wv  = tid >> 6;
    const int li  = l & 31;
    const int sub = l >> 5;

    // XCD-chunked bijective swizzle (gridDim.x = 4*B*H, % 8 == 0)
    const int bid = blockIdx.x;
    const int cpx = gridDim.x >> 3;
    const int wb  = (bid & 7) * cpx + (bid >> 3);
    const int slice = wb & (NSL - 1);
    const int RG  = wb >> 2;          // global row index (bz*128 + row)
    const int bz  = RG >> 7;
    const int row = RG & 127;

    const size_t imgbase = (size_t)bz * C_DIM * HW;
    const int c0  = slice * CPS + wv * 8;   // wave's first channel
    const int px0 = 4 * li;

    const bool has_u = (row > 0), has_d = (row < H_DIM - 1);
    const int rup = has_u ? row - 1 : row;
    const int rdn = has_d ? row + 1 : row;

    const float* pfe = fe + imgbase + (size_t)c0 * HW + row * W_DIM + px0;
    const float* pfm = fu + imgbase + (size_t)c0 * HW + row * W_DIM + px0;
    const float* pfu = fu + imgbase + (size_t)c0 * HW + rup * W_DIM + px0;
    const float* pfd = fu + imgbase + (size_t)c0 * HW + rdn * W_DIM + px0;
    const float4 z4 = make_float4(0.f, 0.f, 0.f, 0.f);

    float4 dk[9];
#pragma unroll
    for (int k = 0; k < 9; ++k) dk[k] = z4;
    float4 fe24 = z4, s24 = z4;

    // R4-measured float4 accumulate (li-masked shuffles handle 32-lane boundary)
    auto acc_row = [&](const float4 f, const float4 v, const int r3) {
        float lft = __shfl_up(v.w, 1);   lft = (li == 0)  ? 0.f : lft;
        float rgt = __shfl_down(v.x, 1); rgt = (li == 31) ? 0.f : rgt;
        dk[r3+0].x += f.x * lft;  dk[r3+1].x += f.x * v.x;  dk[r3+2].x += f.x * v.y;
        dk[r3+0].y += f.y * v.x;  dk[r3+1].y += f.y * v.y;  dk[r3+2].y += f.y * v.z;
        dk[r3+0].z += f.z * v.y;  dk[r3+1].z += f.z * v.z;  dk[r3+2].z += f.z * v.w;
        dk[r3+0].w += f.w * v.z;  dk[r3+1].w += f.w * v.w;  dk[r3+2].w += f.w * rgt;
    };

#pragma unroll
    for (int b = 0; b < 2; ++b) {   // channels c0+4b+sub, c0+4b+2+sub
        const size_t offA = (size_t)(4 * b + sub) * HW;
        const size_t offB = offA + 2 * (size_t)HW;
        float4 fA = LD4(pfe + offA); float4 uA = LD4(pfu + offA);
        float4 mA = LD4(pfm + offA); float4 dA = LD4(pfd + offA);
        float4 fB = LD4(pfe + offB); float4 uB = LD4(pfu + offB);
        float4 mB = LD4(pfm + offB); float4 dB = LD4(pfd + offB);
        if (!has_u) { uA = z4; uB = z4; }
        if (!has_d) { dA = z4; dB = z4; }
        fe24.x += fA.x * fA.x + fB.x * fB.x;
        fe24.y += fA.y * fA.y + fB.y * fB.y;
        fe24.z += fA.z * fA.z + fB.z * fB.z;
        fe24.w += fA.w * fA.w + fB.w * fB.w;
        s24.x += mA.x * mA.x + mB.x * mB.x;
        s24.y += mA.y * mA.y + mB.y * mB.y;
        s24.z += mA.z * mA.z + mB.z * mB.z;
        s24.w += mA.w * mA.w + mB.w * mB.w;
        acc_row(fA, uA, 0); acc_row(fA, mA, 3); acc_row(fA, dA, 6);
        acc_row(fB, uB, 0); acc_row(fB, mB, 3); acc_row(fB, dB, 6);
    }

    // combine the two channel-parity halves (R4-measured)
#pragma unroll
    for (int k = 0; k < 9; ++k) {
        dk[k].x += __shfl_xor(dk[k].x, 32);
        dk[k].y += __shfl_xor(dk[k].y, 32);
        dk[k].z += __shfl_xor(dk[k].z, 32);
        dk[k].w += __shfl_xor(dk[k].w, 32);
    }
    fe24.x += __shfl_xor(fe24.x, 32); fe24.y += __shfl_xor(fe24.y, 32);
    fe24.z += __shfl_xor(fe24.z, 32); fe24.w += __shfl_xor(fe24.w, 32);
    s24.x += __shfl_xor(s24.x, 32);   s24.y += __shfl_xor(s24.y, 32);
    s24.z += __shfl_xor(s24.z, 32);   s24.w += __shfl_xor(s24.w, 32);

    if (sub == 0) {
#pragma unroll
        for (int k = 0; k < 9; ++k) *(float4*)&pl[wv][k * W_DIM + px0] = dk[k];
        *(float4*)&pl[wv][9 * W_DIM + px0]  = fe24;
        *(float4*)&pl[wv][10 * W_DIM + px0] = s24;
    }
    __syncthreads();

    // reduce the 4 wave slots and stream to global partials (float4)
    float4* dst4 = (float4*)(pg + ((size_t)RG * NSL + slice) * PS);
    const float4* p0 = (const float4*)pl[0];
    const float4* p1 = (const float4*)pl[1];
    const float4* p2 = (const float4*)pl[2];
    const float4* p3 = (const float4*)pl[3];
    for (int t = tid; t < PS / 4; t += 256) {
        const float4 a = p0[t], b = p1[t], c = p2[t], d = p3[t];
        float4 s;
        s.x = a.x + b.x + c.x + d.x;
        s.y = a.y + b.y + c.y + d.y;
        s.z = a.z + b.z + c.z + d.z;
        s.w = a.w + b.w + c.w + d.w;
        dst4[t] = s;
    }
}

// ---------------- K3: softmax (from partials) + aggregation + residual ----------------
// Block = (row, channel-group): 256 thr = 4 waves x 8 channels, float4 lanes.
// R10-measured softmax verbatim; R4-measured float4 aggregation.
__global__ __launch_bounds__(256) void k3_agg4(const float* __restrict__ fe,
                                               const float* __restrict__ fu,
                                               const float* __restrict__ pg,
                                               float* __restrict__ out)
{
    __shared__ float dvs[10 * W_DIM];   // summed dot planes + fe2 (5 KB)
    __shared__ float n2r[3 * W_DIM];    // reciprocal neighbor-row fu norms
    __shared__ float wl[9][W_DIM];      // softmax weights

    const int tid = threadIdx.x;
    const int l   = tid & 63;
    const int wv  = tid >> 6;
    const int li  = l & 31;
    const int sub = l >> 5;

    const int bid = blockIdx.x;
    const int cpx = gridDim.x >> 3;
    const int wb  = (bid & 7) * cpx + (bid >> 3);
    const int cg  = wb & (NSL - 1);
    const int RG  = wb >> 2;
    const int bz  = RG >> 7;
    const int row = RG & 127;

    // sum the 4 slices' dot/fe2 planes for this row (float4)
    {
        const float* src = pg + (size_t)RG * NSL * PS;
        const float4* s0 = (const float4*)src;
        const float4* s1 = (const float4*)(src + PS);
        const float4* s2 = (const float4*)(src + 2 * PS);
        const float4* s3 = (const float4*)(src + 3 * PS);
        float4* dv4 = (float4*)dvs;
        for (int t = tid; t < 10 * W_DIM / 4; t += 256) {
            const float4 a = s0[t], b = s1[t], c = s2[t], d = s3[t];
            float4 s;
            s.x = a.x + b.x + c.x + d.x;
            s.y = a.y + b.y + c.y + d.y;
            s.z = a.z + b.z + c.z + d.z;
            s.w = a.w + b.w + c.w + d.w;
            dv4[t] = s;
        }
    }
    // neighbor-row reciprocal norms from norm2 planes (clamped; masked in softmax)
    for (int t = tid; t < 3 * W_DIM; t += 256) {
        const int r = t >> 7, c = t & 127;
        const int nrc = min(max(row + r - 1, 0), H_DIM - 1);
        const float* nb = pg + ((size_t)(bz * H_DIM + nrc) * NSL) * PS + 10 * W_DIM;
        const float s = nb[c] + nb[PS + c] + nb[2 * PS + c] + nb[3 * PS + c];
        n2r[t] = 1.f / fmaxf(sqrtf(s), EPS_N);
    }
    __syncthreads();

    // softmax (threads 0..127, one per pixel) — R10-measured verbatim
    if (tid < W_DIM) {
        const int px = tid;
        const float rfe = 1.f / fmaxf(sqrtf(dvs[9 * W_DIM + px]), EPS_N);
        float cs[9];
        float mx = -1e30f;
#pragma unroll
        for (int k = 0; k < 9; ++k) {
            const int di = k / 3, dj = k % 3;
            const int nr = row + di - 1;
            const int nc = px + dj - 1;
            const bool ok = (nr >= 0 && nr < H_DIM && nc >= 0 && nc < W_DIM);
            const int ncc = min(max(nc, 0), W_DIM - 1);
            const float cv = ok ? dvs[k * W_DIM + px] * rfe * n2r[di * W_DIM + ncc] : 0.f;
            cs[k] = cv;
            mx = fmaxf(mx, cv);
        }
        float sum = 0.f;
#pragma unroll
        for (int k = 0; k < 9; ++k) { cs[k] = __expf(cs[k] - mx); sum += cs[k]; }
        const float is = 1.f / sum;
#pragma unroll
        for (int k = 0; k < 9; ++k) wl[k][px] = cs[k] * is;
    }
    __syncthreads();

    // aggregation for this block's 32 channels (float4 lanes)
    const size_t imgbase = (size_t)bz * C_DIM * HW;
    const int c0  = cg * CPS + wv * 8;
    const int px0 = 4 * li;
    const bool has_u = (row > 0), has_d = (row < H_DIM - 1);
    const int rup = has_u ? row - 1 : row;
    const int rdn = has_d ? row + 1 : row;

    const float* pfe = fe + imgbase + (size_t)c0 * HW + row * W_DIM + px0;
    const float* pfm = fu + imgbase + (size_t)c0 * HW + row * W_DIM + px0;
    const float* pfu = fu + imgbase + (size_t)c0 * HW + rup * W_DIM + px0;
    const float* pfd = fu + imgbase + (size_t)c0 * HW + rdn * W_DIM + px0;
    float* pout = out + imgbase + (size_t)c0 * HW + row * W_DIM + px0;
    const float4 z4 = make_float4(0.f, 0.f, 0.f, 0.f);

    float4 w4[9];
#pragma unroll
    for (int k = 0; k < 9; ++k) w4[k] = *(const float4*)&wl[k][px0];

    auto agg_row = [&](float4& acc, const float4 v, const int r3) {
        float lft = __shfl_up(v.w, 1);   lft = (li == 0)  ? 0.f : lft;
        float rgt = __shfl_down(v.x, 1); rgt = (li == 31) ? 0.f : rgt;
        acc.x += w4[r3+0].x * lft + w4[r3+1].x * v.x + w4[r3+2].x * v.y;
        acc.y += w4[r3+0].y * v.x + w4[r3+1].y * v.y + w4[r3+2].y * v.z;
        acc.z += w4[r3+0].z * v.y + w4[r3+1].z * v.z + w4[r3+2].z * v.w;
        acc.w += w4[r3+0].w * v.z + w4[r3+1].w * v.w + w4[r3+2].w * rgt;
    };

#pragma unroll
    for (int b = 0; b < 2; ++b) {
        const size_t offA = (size_t)(4 * b + sub) * HW;
        const size_t offB = offA + 2 * (size_t)HW;
        float4 fA = LD4(pfe + offA); float4 uA = LD4(pfu + offA);
        float4 mA = LD4(pfm + offA); float4 dA = LD4(pfd + offA);
        float4 fB = LD4(pfe + offB); float4 uB = LD4(pfu + offB);
        float4 mB = LD4(pfm + offB); float4 dB = LD4(pfd + offB);
        if (!has_u) { uA = z4; uB = z4; }
        if (!has_d) { dA = z4; dB = z4; }
        float4 accA = fA;   // residual
        float4 accB = fB;
        agg_row(accA, uA, 0); agg_row(accA, mA, 3); agg_row(accA, dA, 6);
        agg_row(accB, uB, 0); agg_row(accB, mB, 3); agg_row(accB, dB, 6);
        *(float4*)(pout + offA) = accA;
        *(float4*)(pout + offB) = accB;
    }
}

extern "C" void kernel_launch(void* const* d_in, const int* in_sizes, int n_in,
                              void* d_out, int out_size, void* d_ws, size_t ws_size,
                              hipStream_t stream) {
    const float* fe = (const float*)d_in[0];   // fe_lv
    const float* fu = (const float*)d_in[1];   // fused_features
    float* out = (float*)d_out;
    float* pg = (float*)d_ws;                  // B*H*4*1408 floats (11.5 MB @ B=4)
    const int B = in_sizes[0] / (C_DIM * HW);

    dim3 g(B * H_DIM * NSL);                   // 2048 blocks @ B=4
    k2_partial4<<<g, 256, 0, stream>>>(fe, fu, pg);
    k3_agg4<<<g, 256, 0, stream>>>(fe, fu, pg, out);
}